// Round 1
// baseline (92.960 us; speedup 1.0000x reference)
//
#include <hip/hip_runtime.h>
#include <hip/hip_fp16.h>

typedef _Float16 f16x2 __attribute__((ext_vector_type(2)));
typedef _Float16 f16x8 __attribute__((ext_vector_type(8)));
typedef float    f32x4 __attribute__((ext_vector_type(4)));

#define M_DIM   32
#define K_DIM   8192
#define N_DIM   28672
#define KWORDS  1024          // K/8 int32 words per weight row
#define NKB     128           // K/64 scale blocks per row
#define NSPLIT  2             // K splits (combined via atomicAdd)
#define KCHUNK  4096          // K/NSPLIT
#define NCHUNK  32            // KCHUNK/128 LDS chunks
#define NBLK_N  224           // N/128 n-blocks

// out[m,n] = bias[n] (atomicAdd accumulates the K-split partials on top)
__global__ __launch_bounds__(256) void wql_init(const float* __restrict__ bias,
                                                float* __restrict__ out) {
    int n = blockIdx.x * 256 + threadIdx.x;
    int m = blockIdx.y;
    out[(size_t)m * N_DIM + n] = bias[n];
}

__device__ __forceinline__ unsigned pkrtz(float a, float b) {
    return __builtin_bit_cast(unsigned, __builtin_amdgcn_cvt_pkrtz(a, b));
}

// 8 nibbles of one packed word -> 8 fp16 dequantized weights.
// Pair p holds nibbles (p, p+4): magic 0x6400|q == 1024+q exact in fp16;
// cpk = -(1024+8+zq) exact; spk = scale. w = ((1024+q)+c)*s = (q-zp)*s.
__device__ __forceinline__ f16x8 dq_word(unsigned W, f16x2 spk, f16x2 cpk,
                                         unsigned msk, unsigned mgk) {
    union { unsigned u[4]; f16x2 h[4]; f16x8 v; } r;
#pragma unroll
    for (int p = 0; p < 4; ++p) {
        unsigned raw = ((W >> (4 * p)) & msk) | mgk;
        f16x2 f = __builtin_bit_cast(f16x2, raw);
        r.h[p] = (f + cpk) * spk;
    }
    return r.v;
}

__global__ __launch_bounds__(512, 4) void wql_main(
    const float* __restrict__ x, const unsigned* __restrict__ qw,
    const float* __restrict__ scales, const int* __restrict__ qzeros,
    float* __restrict__ out)
{
    // 2 buffers x 512 uint4 = 16 KB. buf layout: [m(32)][word(16)] of 16B,
    // XOR-swizzled: idx = m*16 + (word ^ (m&15))  -> <=2-way bank conflict.
    __shared__ uint4 lds[1024];

    const int tid  = threadIdx.x;
    const int bid  = blockIdx.x;
    const int nblk = bid % NBLK_N;        // consecutive blocks share x chunk (L2)
    const int ks   = bid / NBLK_N;
    const int n0   = nblk * 128;
    const int k0   = ks * KCHUNK;
    const int kb0  = k0 >> 6;             // first global k-block of this split

    const int wv   = tid >> 6;            // wave 0..7 -> 16 n-rows each
    const int lane = tid & 63;
    const int g    = (lane >> 4) & 3;     // k-group
    const int lr   = lane & 15;           // A-row / B-col within tile

    const int n_row = n0 + wv * 16 + lr;
    const unsigned* qwp  = qw + (size_t)n_row * KWORDS + (size_t)kb0 * 8 + 2 * g;
    const float*    srow = scales + (size_t)n_row * NKB;
    const unsigned* zrow = (const unsigned*)qzeros + (size_t)n_row * (NKB / 8);

    // staging: thread t covers x row mt, word slot ws (8 consecutive k)
    const int mt = tid >> 4;              // 0..31
    const int ws = tid & 15;              // 0..15
    const float* xp = x + (size_t)mt * K_DIM + k0 + ws * 8;
    const int woff = mt * 16 + (ws ^ (mt & 15));

    const unsigned msk = 0x000F000Fu, mgk = 0x64006400u;

    f32x4 acc0 = {0.f, 0.f, 0.f, 0.f};
    f32x4 acc1 = {0.f, 0.f, 0.f, 0.f};

    // prologue: stage chunk 0 into buf 0
    {
        float4 ra = ((const float4*)xp)[0];
        float4 rb = ((const float4*)xp)[1];
        uint4 w4 = { pkrtz(ra.x, rb.x), pkrtz(ra.y, rb.y),
                     pkrtz(ra.z, rb.z), pkrtz(ra.w, rb.w) };
        lds[woff] = w4;
    }
    __syncthreads();

    for (int c = 0; c < NCHUNK; ++c) {
        const int buf = (c & 1) * 512;
        float4 ra, rb;
        const bool st = (c + 1 < NCHUNK);
        if (st) {  // issue next chunk's global loads early (hide HBM latency)
            const float4* xs = (const float4*)(xp + (c + 1) * 128);
            ra = xs[0]; rb = xs[1];
        }
#pragma unroll
        for (int u = 0; u < 2; ++u) {
            const int kbg = kb0 + c * 2 + u;           // global k-block (k/64)
            const float s = srow[kbg];
            const unsigned qzw = zrow[kbg >> 3];
            const int zq = (qzw >> ((kbg & 7) * 4)) & 0xF;
            const _Float16 sh = (_Float16)s;
            const _Float16 ch = (_Float16)(-(float)(1032 + zq)); // -(1024+8+zq)
            const f16x2 spk = { sh, sh };
            const f16x2 cpk = { ch, ch };

            const uint2 wq = *(const uint2*)(qwp + (size_t)(c * 2 + u) * 8);
            f16x8 a0 = dq_word(wq.x, spk, cpk, msk, mgk);   // k-step t=0
            f16x8 a1 = dq_word(wq.y, spk, cpk, msk, mgk);   // k-step t=1

            const int wb = u * 8 + 2 * g;                   // local word base
            f16x8 b00 = __builtin_bit_cast(f16x8, lds[buf + lr * 16        + ((wb    ) ^ lr)]);
            f16x8 b01 = __builtin_bit_cast(f16x8, lds[buf + (lr + 16) * 16 + ((wb    ) ^ lr)]);
            f16x8 b10 = __builtin_bit_cast(f16x8, lds[buf + lr * 16        + ((wb + 1) ^ lr)]);
            f16x8 b11 = __builtin_bit_cast(f16x8, lds[buf + (lr + 16) * 16 + ((wb + 1) ^ lr)]);

            acc0 = __builtin_amdgcn_mfma_f32_16x16x32_f16(a0, b00, acc0, 0, 0, 0);
            acc1 = __builtin_amdgcn_mfma_f32_16x16x32_f16(a0, b01, acc1, 0, 0, 0);
            acc0 = __builtin_amdgcn_mfma_f32_16x16x32_f16(a1, b10, acc0, 0, 0, 0);
            acc1 = __builtin_amdgcn_mfma_f32_16x16x32_f16(a1, b11, acc1, 0, 0, 0);
        }
        if (st) {
            uint4 w4 = { pkrtz(ra.x, rb.x), pkrtz(ra.y, rb.y),
                         pkrtz(ra.z, rb.z), pkrtz(ra.w, rb.w) };
            lds[((c + 1) & 1) * 512 + woff] = w4;
        }
        __syncthreads();
    }

    // C/D: col(m) = lane&15, row(n within tile) = 4*(lane>>4)+reg
    float* o0 = out + (size_t)lr * N_DIM        + n0 + wv * 16 + 4 * g;
    float* o1 = out + (size_t)(lr + 16) * N_DIM + n0 + wv * 16 + 4 * g;
#pragma unroll
    for (int r = 0; r < 4; ++r) {
        atomicAdd(o0 + r, acc0[r]);
        atomicAdd(o1 + r, acc1[r]);
    }
}

extern "C" void kernel_launch(void* const* d_in, const int* in_sizes, int n_in,
                              void* d_out, int out_size, void* d_ws, size_t ws_size,
                              hipStream_t stream) {
    const float*    x      = (const float*)d_in[0];
    const unsigned* qwght  = (const unsigned*)d_in[1];
    const float*    scales = (const float*)d_in[2];
    const int*      qzeros = (const int*)d_in[3];
    const float*    bias   = (const float*)d_in[4];
    float* out = (float*)d_out;

    wql_init<<<dim3(N_DIM / 256, M_DIM), 256, 0, stream>>>(bias, out);
    wql_main<<<dim3(NBLK_N * NSPLIT), 512, 0, stream>>>(x, qwght, scales, qzeros, out);
}